// Round 4
// baseline (1382.282 us; speedup 1.0000x reference)
//
#include <hip/hip_runtime.h>
#include <hip/hip_bf16.h>
#include <stdint.h>

#define NN   100000
#define EE   3200000
#define HD   128

typedef short v8s __attribute__((ext_vector_type(8)));
typedef float v4f __attribute__((ext_vector_type(4)));

__device__ __forceinline__ unsigned short f2bf(float f){
  union { float f; unsigned int i; } v; v.f = f;
  unsigned int r = v.i + 0x7fffu + ((v.i >> 16) & 1u);
  return (unsigned short)(r >> 16);
}
__device__ __forceinline__ unsigned cvt2(float a, float b){
  return (unsigned)f2bf(a) | ((unsigned)f2bf(b) << 16);
}
__device__ __forceinline__ uint4 pack8(float4 lo, float4 hi){
  uint4 r;
  r.x = cvt2(lo.x, lo.y);
  r.y = cvt2(lo.z, lo.w);
  r.z = cvt2(hi.x, hi.y);
  r.w = cvt2(hi.z, hi.w);
  return r;
}
// accumulate 8 bf16 features packed in a uint4 into float a[8]
__device__ __forceinline__ void acc8(float* a, uint4 u){
  union {unsigned int i; float f;} t;
  t.i = u.x << 16;         a[0] += t.f;
  t.i = u.x & 0xffff0000u; a[1] += t.f;
  t.i = u.y << 16;         a[2] += t.f;
  t.i = u.y & 0xffff0000u; a[3] += t.f;
  t.i = u.z << 16;         a[4] += t.f;
  t.i = u.z & 0xffff0000u; a[5] += t.f;
  t.i = u.w << 16;         a[6] += t.f;
  t.i = u.w & 0xffff0000u; a[7] += t.f;
}

// ---------------- weights -> bf16 (once) ----------------
__global__ __launch_bounds__(256)
void k_cvtw(const float* __restrict__ Wm, const float* __restrict__ Wc,
            const float* __restrict__ Wl1, const float* __restrict__ Wr1,
            unsigned short* __restrict__ Wmb, unsigned short* __restrict__ Wcb,
            unsigned short* __restrict__ Wl1b, unsigned short* __restrict__ Wr1b)
{
  int p = blockIdx.x*blockDim.x + threadIdx.x;   // float-pair index
  const float* s; unsigned* d; int off;
  if      (p <  81920){ s = Wm;  d = (unsigned*)Wmb;  off = p; }
  else if (p <  94208){ s = Wc;  d = (unsigned*)Wcb;  off = p -  81920; }
  else if (p < 102400){ s = Wl1; d = (unsigned*)Wl1b; off = p -  94208; }
  else if (p < 110592){ s = Wr1; d = (unsigned*)Wr1b; off = p - 102400; }
  else return;
  float2 v = ((const float2*)s)[off];
  d[off] = cvt2(v.x, v.y);
}

// ---------------- graph build ----------------
__global__ void k_zero(int* p, int n){
  int i = blockIdx.x*blockDim.x + threadIdx.x; if (i < n) p[i] = 0;
}
// pass 1: 8-way banked histogram + per-edge sub-rank. Bank = edge_index & 7
// (8x less per-cache-line atomic serialization than a single cnt[] array).
__global__ __launch_bounds__(256)
void k_histrank(const int* __restrict__ dst, int* __restrict__ cnt2,
                int* __restrict__ rank, int e4){
  int i = blockIdx.x*blockDim.x + threadIdx.x;
  if (i >= e4) return;
  int4 d4 = ((const int4*)dst)[i];
  int b = (4*i) & 7;     // banks b, b+1, b+2, b+3
  int4 r4;
  r4.x = atomicAdd(&cnt2[(b+0)*NN + d4.x], 1);
  r4.y = atomicAdd(&cnt2[(b+1)*NN + d4.y], 1);
  r4.z = atomicAdd(&cnt2[(b+2)*NN + d4.z], 1);
  r4.w = atomicAdd(&cnt2[(b+3)*NN + d4.w], 1);
  ((int4*)rank)[i] = r4;
}
// fold 8 banks: cnt2 becomes per-bank exclusive offset; cnt = total degree
__global__ __launch_bounds__(256)
void k_suboff(int* __restrict__ cnt2, int* __restrict__ cnt, int n){
  int d = blockIdx.x*blockDim.x + threadIdx.x;
  if (d >= n) return;
  int s = 0;
#pragma unroll
  for (int k = 0; k < 8; k++){
    int v = cnt2[k*n + d];
    cnt2[k*n + d] = s;
    s += v;
  }
  cnt[d] = s;
}
__global__ __launch_bounds__(1024)
void k_scan1(const int* __restrict__ cnt, int* __restrict__ offs, int* __restrict__ blksum, int n){
  __shared__ int lds[1024];
  int t = threadIdx.x; int i = blockIdx.x*1024 + t;
  int v = (i < n) ? cnt[i] : 0;
  lds[t] = v; __syncthreads();
  for (int s = 1; s < 1024; s <<= 1){
    int add = (t >= s) ? lds[t-s] : 0;
    __syncthreads();
    lds[t] += add;
    __syncthreads();
  }
  if (i < n) offs[i] = lds[t] - v;           // exclusive
  if (t == 1023) blksum[blockIdx.x] = lds[1023];
}
__global__ __launch_bounds__(128)
void k_scan2(int* __restrict__ blksum, int nb){
  __shared__ int lds[128];
  int t = threadIdx.x;
  int v = (t < nb) ? blksum[t] : 0;
  lds[t] = v; __syncthreads();
  for (int s = 1; s < 128; s <<= 1){
    int a = (t >= s) ? lds[t-s] : 0;
    __syncthreads();
    lds[t] += a;
    __syncthreads();
  }
  if (t < nb) blksum[t] = lds[t] - v;        // exclusive
}
__global__ __launch_bounds__(1024)
void k_scan3(int* __restrict__ offs, const int* __restrict__ blksum, int n){
  int i = blockIdx.x*1024 + threadIdx.x;
  if (i < n) offs[i] += blksum[blockIdx.x];
}
// pass 2: atomic-free placement: pos = offs[dst] + bank_offset + sub-rank
__global__ __launch_bounds__(256)
void k_place(const int* __restrict__ src, const int* __restrict__ dst,
             const int* __restrict__ offs, const int* __restrict__ rank,
             const int* __restrict__ suboff, int* __restrict__ ssrc, int e4){
  int i = blockIdx.x*blockDim.x + threadIdx.x;
  if (i >= e4) return;
  int4 s4 = ((const int4*)src)[i];
  int4 d4 = ((const int4*)dst)[i];
  int4 r4 = ((const int4*)rank)[i];
  int b = (4*i) & 7;
  ssrc[offs[d4.x] + suboff[(b+0)*NN + d4.x] + r4.x] = s4.x;
  ssrc[offs[d4.y] + suboff[(b+1)*NN + d4.y] + r4.y] = s4.y;
  ssrc[offs[d4.z] + suboff[(b+2)*NN + d4.z] + r4.z] = s4.z;
  ssrc[offs[d4.w] + suboff[(b+3)*NN + d4.w] + r4.w] = s4.w;
}

// -------- bf16-MFMA GEMM: C_bf16[M,128] = relu?(A@B^T + bias), B pre-converted bf16 --------
__device__ __forceinline__ void gemm_issue(int t, int T0, int M, int gm, int r0, int c8,
    const void* __restrict__ A0, int lda0, int a0f32,
    const void* __restrict__ A1, int lda1, int a1f32,
    const unsigned short* __restrict__ B0, int ldb0,
    const unsigned short* __restrict__ B1, int ldb1,
    uint4* as, uint4* bs)
{
  const void* Ag; const unsigned short* Bg; int la, lb, ko, af32;
  if (t < T0){ Ag = A0; la = lda0; af32 = a0f32; Bg = B0; lb = ldb0; ko = t*64; }
  else       { Ag = A1; la = lda1; af32 = a1f32; Bg = B1; lb = ldb1; ko = (t-T0)*64; }
#pragma unroll
  for (int p = 0; p < 4; p++){
    int row  = r0 + p*32;
    int grow = gm + row;
    if (grow < M){
      if (af32){
        const float* ap = (const float*)Ag + (size_t)grow*la + ko + c8;
        as[p] = pack8(*(const float4*)ap, *(const float4*)(ap + 4));
      } else {
        as[p] = *(const uint4*)((const unsigned short*)Ag + (size_t)grow*la + ko + c8);
      }
    } else {
      as[p] = make_uint4(0u,0u,0u,0u);
    }
    bs[p] = *(const uint4*)(Bg + (size_t)row*lb + ko + c8);
  }
}

__global__ __launch_bounds__(256)
void k_gemm(int M,
            const void* __restrict__ A0, int lda0, int K0, int a0f32,
            const void* __restrict__ A1, int lda1, int K1, int a1f32,
            const unsigned short* __restrict__ B0, int ldb0,
            const unsigned short* __restrict__ B1, int ldb1,
            const float* __restrict__ bias, int do_relu,
            unsigned short* __restrict__ C, int ldc)
{
  __shared__ unsigned short Abuf[128*72];   // BK=64 bf16, pad 8
  __shared__ unsigned short Bbuf[128*72];
  const int tid = threadIdx.x;
  const int gm  = blockIdx.x * 128;
  const int T0  = K0 >> 6;
  const int T   = (K0 + K1) >> 6;

  const int r0 = tid >> 3;          // 0..31
  const int c8 = (tid & 7) * 8;     // 0..56

  const int lane = tid & 63;
  const int w  = tid >> 6;
  const int wm = w >> 1, wn = w & 1;
  const int l15 = lane & 15, q = lane >> 4;

  v4f acc[4][4];
#pragma unroll
  for (int mi = 0; mi < 4; mi++)
#pragma unroll
    for (int ni = 0; ni < 4; ni++){ v4f z = {0.f,0.f,0.f,0.f}; acc[mi][ni] = z; }

  uint4 aS[4], bS[4];
  gemm_issue(0, T0, M, gm, r0, c8, A0, lda0, a0f32, A1, lda1, a1f32,
             B0, ldb0, B1, ldb1, aS, bS);

  for (int t = 0; t < T; ++t){
#pragma unroll
    for (int p = 0; p < 4; p++){
      int row = r0 + p*32;
      *(uint4*)(Abuf + row*72 + c8) = aS[p];
      *(uint4*)(Bbuf + row*72 + c8) = bS[p];
    }
    __syncthreads();
    if (t + 1 < T)
      gemm_issue(t+1, T0, M, gm, r0, c8, A0, lda0, a0f32, A1, lda1, a1f32,
                 B0, ldb0, B1, ldb1, aS, bS);
#pragma unroll
    for (int kk = 0; kk < 64; kk += 32){
      v8s af[4], bf[4];
#pragma unroll
      for (int mi = 0; mi < 4; mi++)
        af[mi] = *(const v8s*)(Abuf + (wm*64 + mi*16 + l15)*72 + kk + q*8);
#pragma unroll
      for (int ni = 0; ni < 4; ni++)
        bf[ni] = *(const v8s*)(Bbuf + (wn*64 + ni*16 + l15)*72 + kk + q*8);
#pragma unroll
      for (int mi = 0; mi < 4; mi++)
#pragma unroll
        for (int ni = 0; ni < 4; ni++)
          acc[mi][ni] = __builtin_amdgcn_mfma_f32_16x16x32_bf16(af[mi], bf[ni], acc[mi][ni], 0, 0, 0);
    }
    __syncthreads();
  }

  // epilogue: D col = lane&15, row = (lane>>4)*4 + reg (m89-verified mapping)
#pragma unroll
  for (int ni = 0; ni < 4; ni++){
    int n = wn*64 + ni*16 + l15;
    float bv = bias ? bias[n] : 0.0f;
#pragma unroll
    for (int mi = 0; mi < 4; mi++){
#pragma unroll
      for (int r = 0; r < 4; r++){
        int row = gm + wm*64 + mi*16 + q*4 + r;
        if (row < M){
          float v = acc[mi][ni][r] + bv;
          if (do_relu) v = v > 0.f ? v : 0.f;
          C[(size_t)row*ldc + n] = f2bf(v);
        }
      }
    }
  }
}

// ---------------- layer-1 aggregate + finish + fused C=4 projections ----------------
__global__ __launch_bounds__(256)
void k_agg1(const int* __restrict__ offs, const int* __restrict__ cnt,
            const int* __restrict__ ssrc,
            const unsigned short* __restrict__ y1,
            const unsigned short* __restrict__ z1,
            const float* __restrict__ Wl2,
            const float* __restrict__ Wr2,
            const float* __restrict__ bl2,
            float* __restrict__ y2, float* __restrict__ r2, int n)
{
  int wid  = (blockIdx.x * blockDim.x + threadIdx.x) >> 6;
  int lane = threadIdx.x & 63;
  if (wid >= n) return;
  int start = offs[wid];
  int deg   = cnt[wid];
  const uint4* y1q = (const uint4*)y1;   // one row = 16 uint4
  const int g = lane >> 4;               // 0..3: edge within quad
  const int c = lane & 15;               // feature chunk: feats 8c..8c+7

  float a[8];
#pragma unroll
  for (int j = 0; j < 8; j++) a[j] = 0.f;

  for (int base = 0; base < deg; base += 64){
    int idx = base + lane;
    int sl  = (idx < deg) ? ssrc[start + idx] : 0;
    int m   = deg - base; if (m > 64) m = 64;
    int quads = (m + 3) >> 2;
    int tq = 0;
    for (; tq + 2 <= quads; tq += 2){
      int e0 = tq*4 + g, e1 = e0 + 4;
      int i0 = e0 < m ? e0 : m-1;
      int i1 = e1 < m ? e1 : m-1;
      int s0 = __shfl(sl, i0, 64);
      int s1 = __shfl(sl, i1, 64);
      uint4 u0 = y1q[(size_t)s0*16 + c];
      uint4 u1 = y1q[(size_t)s1*16 + c];
      if (e0 < m) acc8(a, u0);
      if (e1 < m) acc8(a, u1);
    }
    if (tq < quads){
      int e0 = tq*4 + g;
      int i0 = e0 < m ? e0 : m-1;
      int s0 = __shfl(sl, i0, 64);
      uint4 u0 = y1q[(size_t)s0*16 + c];
      if (e0 < m) acc8(a, u0);
    }
  }
#pragma unroll
  for (int j = 0; j < 8; j++){
    a[j] += __shfl_xor(a[j], 16, 64);
    a[j] += __shfl_xor(a[j], 32, 64);
  }

  float scale = 1.0f / (float)(deg > 0 ? deg : 1);
  uint4 zu = ((const uint4*)z1)[(size_t)wid*16 + c];
  float x8[8];
  {
    union {unsigned int i; float f;} t;
    t.i = zu.x << 16;         x8[0] = t.f;
    t.i = zu.x & 0xffff0000u; x8[1] = t.f;
    t.i = zu.y << 16;         x8[2] = t.f;
    t.i = zu.y & 0xffff0000u; x8[3] = t.f;
    t.i = zu.z << 16;         x8[4] = t.f;
    t.i = zu.z & 0xffff0000u; x8[5] = t.f;
    t.i = zu.w << 16;         x8[6] = t.f;
    t.i = zu.w & 0xffff0000u; x8[7] = t.f;
  }
#pragma unroll
  for (int j = 0; j < 8; j++){
    float v = a[j]*scale + x8[j];
    x8[j] = v > 0.f ? v : 0.f;
  }

  float pl[4], pr[4];
#pragma unroll
  for (int cc = 0; cc < 4; cc++){
    const float* wl = Wl2 + cc*128 + 8*c;
    const float* wr = Wr2 + cc*128 + 8*c;
    float4 wl0 = *(const float4*)wl, wl1 = *(const float4*)(wl + 4);
    float4 wr0 = *(const float4*)wr, wr1 = *(const float4*)(wr + 4);
    pl[cc] = x8[0]*wl0.x + x8[1]*wl0.y + x8[2]*wl0.z + x8[3]*wl0.w
           + x8[4]*wl1.x + x8[5]*wl1.y + x8[6]*wl1.z + x8[7]*wl1.w;
    pr[cc] = x8[0]*wr0.x + x8[1]*wr0.y + x8[2]*wr0.z + x8[3]*wr0.w
           + x8[4]*wr1.x + x8[5]*wr1.y + x8[6]*wr1.z + x8[7]*wr1.w;
  }
#pragma unroll
  for (int off = 8; off >= 1; off >>= 1){
#pragma unroll
    for (int cc = 0; cc < 4; cc++){
      pl[cc] += __shfl_xor(pl[cc], off, 64);
      pr[cc] += __shfl_xor(pr[cc], off, 64);
    }
  }
  if (lane == 0){
    float4 o; o.x = pl[0]; o.y = pl[1]; o.z = pl[2]; o.w = pl[3];
    *(float4*)(y2 + (size_t)wid*4) = o;
    float4 b = *(const float4*)bl2;
    float4 p; p.x = pr[0]+b.x; p.y = pr[1]+b.y; p.z = pr[2]+b.z; p.w = pr[3]+b.w;
    *(float4*)(r2 + (size_t)wid*4) = p;
  }
}

// ---------------- layer-2 aggregate + fp32 output ----------------
__global__ __launch_bounds__(256)
void k_agg2(const int* __restrict__ offs, const int* __restrict__ cnt,
            const int* __restrict__ ssrc,
            const float* __restrict__ y2, const float* __restrict__ r2,
            float* __restrict__ out, int n)
{
  int wid  = (blockIdx.x * blockDim.x + threadIdx.x) >> 6;
  int lane = threadIdx.x & 63;
  if (wid >= n) return;
  int start = offs[wid], deg = cnt[wid];
  float a0 = 0.f, a1 = 0.f, a2 = 0.f, a3 = 0.f;
  for (int base = 0; base < deg; base += 64){
    int idx = base + lane;
    if (idx < deg){
      int s = ssrc[start + idx];
      float4 v = *(const float4*)(y2 + (size_t)s*4);
      a0 += v.x; a1 += v.y; a2 += v.z; a3 += v.w;
    }
  }
#pragma unroll
  for (int off = 32; off >= 1; off >>= 1){
    a0 += __shfl_xor(a0, off, 64);
    a1 += __shfl_xor(a1, off, 64);
    a2 += __shfl_xor(a2, off, 64);
    a3 += __shfl_xor(a3, off, 64);
  }
  if (lane == 0){
    float sc = 1.0f / (float)(deg > 0 ? deg : 1);
    float4 r = *(const float4*)(r2 + (size_t)wid*4);
    float4 o;
    o.x = a0*sc + r.x; o.y = a1*sc + r.y; o.z = a2*sc + r.z; o.w = a3*sc + r.w;
    *(float4*)(out + (size_t)wid*4) = o;
  }
}

extern "C" void kernel_launch(void* const* d_in, const int* in_sizes, int n_in,
                              void* d_out, int out_size, void* d_ws, size_t ws_size,
                              hipStream_t stream)
{
  (void)in_sizes; (void)n_in; (void)out_size; (void)ws_size;
  const float* clinical = (const float*)d_in[0];
  const float* mel      = (const float*)d_in[1];
  const int*   ei       = (const int*)d_in[2];
  const float* Wm  = (const float*)d_in[3];
  const float* bm  = (const float*)d_in[4];
  const float* Wc  = (const float*)d_in[5];
  const float* bc  = (const float*)d_in[6];
  const float* Wl1 = (const float*)d_in[7];
  const float* bl1 = (const float*)d_in[8];
  const float* Wr1 = (const float*)d_in[9];
  const float* Wl2 = (const float*)d_in[10];
  const float* bl2 = (const float*)d_in[11];
  const float* Wr2 = (const float*)d_in[12];
  const int* src = ei;
  const int* dst = ei + EE;

  char* w = (char*)d_ws;
  auto alloc = [&](size_t sz){ void* p = (void*)w; w += (sz + 255) & ~(size_t)255; return p; };
  unsigned short* mel_h = (unsigned short*)alloc((size_t)NN*HD*2);  // reused as y1 after GEMM2
  unsigned short* x     = (unsigned short*)alloc((size_t)NN*HD*2);
  unsigned short* z1    = (unsigned short*)alloc((size_t)NN*HD*2);
  int*   ssrc   = (int*)alloc((size_t)EE*4);
  int*   rank   = (int*)alloc((size_t)EE*4);
  int*   cnt2   = (int*)alloc((size_t)NN*8*4);   // 8 banked counters / suboffs
  int*   cnt    = (int*)alloc((size_t)NN*4);
  int*   offs   = (int*)alloc((size_t)NN*4);
  int*   blksum = (int*)alloc(4096);
  float* y2     = (float*)alloc((size_t)NN*4*4);
  float* r2     = (float*)alloc((size_t)NN*4*4);
  unsigned short* Wmb  = (unsigned short*)alloc((size_t)128*1280*2);
  unsigned short* Wcb  = (unsigned short*)alloc((size_t)128*192*2);
  unsigned short* Wl1b = (unsigned short*)alloc((size_t)128*128*2);
  unsigned short* Wr1b = (unsigned short*)alloc((size_t)128*128*2);

  // weights -> bf16 (once; removes per-block B conversion in all GEMMs)
  k_cvtw<<<432, 256, 0, stream>>>(Wm, Wc, Wl1, Wr1, Wmb, Wcb, Wl1b, Wr1b);

  // --- CSR build: banked hist+rank (1 atomic/edge), fold, scan, atomic-free place ---
  k_zero<<<(NN*8+255)/256, 256, 0, stream>>>(cnt2, NN*8);
  k_histrank<<<(EE/4+255)/256, 256, 0, stream>>>(dst, cnt2, rank, EE/4);
  k_suboff<<<(NN+255)/256, 256, 0, stream>>>(cnt2, cnt, NN);
  int nblk = (NN + 1023) / 1024;  // 98
  k_scan1<<<nblk, 1024, 0, stream>>>(cnt, offs, blksum, NN);
  k_scan2<<<1, 128, 0, stream>>>(blksum, nblk);
  k_scan3<<<nblk, 1024, 0, stream>>>(offs, blksum, NN);
  k_place<<<(EE/4+255)/256, 256, 0, stream>>>(src, dst, offs, rank, cnt2, ssrc, EE/4);

  int gmb = (NN + 127) / 128;     // 782 row tiles
  // mel_h = relu(mel @ Wm^T + bm)          (A fp32, B bf16)
  k_gemm<<<gmb, 256, 0, stream>>>(NN, mel, 1280, 1280, 1, nullptr, 0, 0, 0,
                                  Wmb, 1280, nullptr, 0, bm, 1, mel_h, HD);
  // x = relu([clinical | mel_h] @ Wc^T + bc)   (seg0 fp32 K=64, seg1 bf16 K=128)
  k_gemm<<<gmb, 256, 0, stream>>>(NN, clinical, 64, 64, 1, mel_h, HD, HD, 0,
                                  Wcb, 192, Wcb + 64, 192, bc, 1, x, HD);
  // y1 = x @ Wl1^T   (into mel_h buffer — mel_h dead after GEMM2)
  unsigned short* y1 = mel_h;
  k_gemm<<<gmb, 256, 0, stream>>>(NN, x, HD, HD, 0, nullptr, 0, 0, 0,
                                  Wl1b, HD, nullptr, 0, nullptr, 0, y1, HD);
  // z1 = x @ Wr1^T + bl1
  k_gemm<<<gmb, 256, 0, stream>>>(NN, x, HD, HD, 0, nullptr, 0, 0, 0,
                                  Wr1b, HD, nullptr, 0, bl1, 0, z1, HD);

  // layer-1 aggregate + relu + fused layer-2 projections
  k_agg1<<<(NN+3)/4, 256, 0, stream>>>(offs, cnt, ssrc, y1, z1, Wl2, Wr2, bl2, y2, r2, NN);
  // layer-2 aggregate + fp32 output
  k_agg2<<<(NN+3)/4, 256, 0, stream>>>(offs, cnt, ssrc, y2, r2, (float*)d_out, NN);
}